// Round 14
// baseline (2159.775 us; speedup 1.0000x reference)
//
#include <hip/hip_runtime.h>

#define B_    4
#define N_    20000
#define M_    20000
#define K_    16
#define CIN   64
#define CMID  16
#define COUT  67            // CIN + 3 additional channels
#define PPB   4             // one point per wave, 4 waves per block
#define LSTR  17            // padded LDS transpose stride (f32)
#define NXCD  8

typedef float float4_ __attribute__((ext_vector_type(4)));

// Single per-wave LDS buffer, 1140 f32 (4560 B):
//   phase 1: offsets 0..255   = wn[16][16] staging (FMA + tail reads)
//   phase 2: offsets 0..1137  = output transpose buf rows 0..66 (stride 17)
// Legal aliasing: tail-compute (last wn reader) runs BEFORE the main
// transpose overwrites 0..255; same-wave LDS ops are program-ordered.
// 4 x 4560 B = 18.2 KB/block -> 8 blocks/CU; launch_bounds(256,8) -> VGPR<=64
// => 32 waves/CU (up from 24).

__global__ __launch_bounds__(256, 8) void pconv_kernel(
    const float* __restrict__ in_feats,   // [B, N, 64]
    const int*   __restrict__ inds,       // [B, M, 16]
    const float* __restrict__ wn,         // [B, M, 16, 16]
    const float* __restrict__ addl,       // [B, M, 16, 3]
    float*       __restrict__ out)        // [B, M, 1072]
{
    __shared__ float lds[PPB][1140];

    const int tid  = threadIdx.x;
    const int lane = tid & 63;
    const int wav  = tid >> 6;

    // bijective XCD swizzle: 20000 blocks -> 2500 contiguous per XCD slot
    const int qx  = gridDim.x / NXCD;                    // 2500
    const int swz = (blockIdx.x % NXCD) * qx + blockIdx.x / NXCD;

    const int bp = __builtin_amdgcn_readfirstlane(swz * PPB + wav);
    const int b  = bp / M_;

    const int*   pinds = inds + (long)bp * K_;
    const float* pwn   = wn   + (long)bp * (K_ * CMID);
    const float* padd  = addl + (long)bp * (K_ * 3);
    const float* bfeat = in_feats + (long)b * N_ * CIN;

    float* lo = &lds[wav][0];

    // ---- wn: read-once stream -> non-temporal load (don't pollute L2) ----
    float4_ wstage = __builtin_nontemporal_load((const float4_*)pwn + lane);

    // ---- 16 neighbor indices -> SGPRs ----
    int idxs[K_];
    #pragma unroll
    for (int k = 0; k < K_; ++k) idxs[k] = pinds[k];

    // ---- issue ALL 16 gathers before any consumption (max MLP) ----
    float f[K_];
    #pragma unroll
    for (int k = 0; k < K_; ++k)
        f[k] = bfeat[(long)idxs[k] * CIN + lane];        // 256B coalesced each

    // stage wn into LDS offsets 0..255
    *(float4_*)(lo + lane * 4) = wstage;

    // ---- FMA phase: wn via uniform ds_read_b128 broadcasts ----
    float acc[CMID];
    #pragma unroll
    for (int w = 0; w < CMID; ++w) acc[w] = 0.f;

    #pragma unroll
    for (int k = 0; k < K_; ++k) {
        const float* lw = lo + k * CMID;
        float4_ w0 = *(const float4_*)(lw + 0);
        float4_ w1 = *(const float4_*)(lw + 4);
        float4_ w2 = *(const float4_*)(lw + 8);
        float4_ w3 = *(const float4_*)(lw + 12);
        #pragma unroll
        for (int e = 0; e < 4; ++e) {
            acc[0  + e] += f[k] * w0[e];
            acc[4  + e] += f[k] * w1[e];
            acc[8  + e] += f[k] * w2[e];
            acc[12 + e] += f[k] * w3[e];
        }
    }

    // ---- tail channels FIRST (last reader of wn region 0..255) ----
    // writes rows 64..66 -> offsets 1088..1137 (no overlap with 0..255)
    const int t  = lane >> 4;
    const int wt = lane & 15;
    if (lane < 48) {
        float acc2 = 0.f;
        #pragma unroll
        for (int k = 0; k < K_; ++k) {
            float a0 = padd[k * 3 + 0];                  // uniform s_loads
            float a1 = padd[k * 3 + 1];
            float a2 = padd[k * 3 + 2];
            float av = (t == 0) ? a0 : (t == 1) ? a1 : a2;
            acc2 += av * lo[k * CMID + wt];              // broadcast x3, conflict-free
        }
        lo[(CIN + t) * LSTR + wt] = acc2;
    }

    // ---- main transpose (overwrites wn region — now dead) ----
    #pragma unroll
    for (int w = 0; w < CMID; ++w)
        lo[lane * LSTR + w] = acc[w];                    // 17-stride: <=2-way banks

    // ---- readback in store-contiguous order; NT stores 4x1KB + 192B ----
    float* pout = out + (long)bp * (COUT * CMID);
    const int q = lane >> 2;
    const int r = lane & 3;
    #pragma unroll
    for (int p = 0; p < 4; ++p) {
        const float* src = lo + (p * 16 + q) * LSTR + 4 * r;
        float4_ v = { src[0], src[1], src[2], src[3] };
        __builtin_nontemporal_store(v, (float4_*)(pout + p * 256 + lane * 4));
    }
    if (lane < 12) {
        const float* src = lo + (CIN + q) * LSTR + 4 * r;
        float4_ v = { src[0], src[1], src[2], src[3] };
        __builtin_nontemporal_store(v, (float4_*)(pout + 1024 + lane * 4));
    }
}

extern "C" void kernel_launch(void* const* d_in, const int* in_sizes, int n_in,
                              void* d_out, int out_size, void* d_ws, size_t ws_size,
                              hipStream_t stream) {
    const float* in_feats = (const float*)d_in[0];
    const int*   ninds    = (const int*)d_in[1];
    const float* wnp      = (const float*)d_in[2];
    const float* addl     = (const float*)d_in[3];
    float*       outp     = (float*)d_out;

    const int total_points = B_ * M_;            // 80000
    dim3 grid(total_points / PPB);               // 20000 blocks, 1 point/wave
    dim3 block(256);
    pconv_kernel<<<grid, block, 0, stream>>>(in_feats, ninds, wnp, addl, outp);
}

// Round 15
// 2093.570 us; speedup vs baseline: 1.0316x; 1.0316x over previous
//
#include <hip/hip_runtime.h>

#define B_    4
#define N_    20000
#define M_    20000
#define K_    16
#define CIN   64
#define CMID  16
#define COUT  67            // CIN + 3 additional channels
#define PPB   4             // one point per wave, 4 waves per block
#define LSTR  17            // padded LDS transpose stride (f32)
#define NXCD  8

typedef float float4_ __attribute__((ext_vector_type(4)));

// Single per-wave LDS buffer, 1140 f32 (4560 B):
//   phase 1: offsets 0..255  = wn[16][16] staging
//   phase 2: offsets 0..1137 = transpose buf rows 0..66 (stride 17)
// Aliasing validated R14 (absmax 0.0): tail-compute (last wn reader) runs
// before the main transpose overwrites 0..255; same-wave LDS is ordered.
// 18.2 KB/block. launch_bounds(256,7): VGPR cap 72 — fits ~60 live regs
// (R14's cap of 64 spilled catastrophically; 85 at bounds-6 was R13).

__global__ __launch_bounds__(256, 7) void pconv_kernel(
    const float* __restrict__ in_feats,   // [B, N, 64]
    const int*   __restrict__ inds,       // [B, M, 16]
    const float* __restrict__ wn,         // [B, M, 16, 16]
    const float* __restrict__ addl,       // [B, M, 16, 3]
    float*       __restrict__ out)        // [B, M, 1072]
{
    __shared__ float lds[PPB][1140];

    const int tid  = threadIdx.x;
    const int lane = tid & 63;
    const int wav  = tid >> 6;

    // bijective XCD swizzle: 20000 blocks -> 2500 contiguous per XCD slot
    const int qx  = gridDim.x / NXCD;                    // 2500
    const int swz = (blockIdx.x % NXCD) * qx + blockIdx.x / NXCD;

    const int bp = __builtin_amdgcn_readfirstlane(swz * PPB + wav);
    const int b  = bp / M_;

    const int*   pinds = inds + (long)bp * K_;
    const float* pwn   = wn   + (long)bp * (K_ * CMID);
    const float* padd  = addl + (long)bp * (K_ * 3);
    const float* bfeat = in_feats + (long)b * N_ * CIN;

    float* lo = &lds[wav][0];

    // ---- wn: read-once stream -> non-temporal load (don't pollute L2) ----
    float4_ wstage = __builtin_nontemporal_load((const float4_*)pwn + lane);

    // ---- 16 neighbor indices -> SGPRs ----
    int idxs[K_];
    #pragma unroll
    for (int k = 0; k < K_; ++k) idxs[k] = pinds[k];

    // ---- issue ALL 16 gathers before any consumption (max MLP) ----
    float f[K_];
    #pragma unroll
    for (int k = 0; k < K_; ++k)
        f[k] = bfeat[(long)idxs[k] * CIN + lane];        // 256B coalesced each

    // stage wn into LDS offsets 0..255
    *(float4_*)(lo + lane * 4) = wstage;

    // ---- FMA phase: wn via uniform ds_read_b128 broadcasts ----
    float acc[CMID];
    #pragma unroll
    for (int w = 0; w < CMID; ++w) acc[w] = 0.f;

    #pragma unroll
    for (int k = 0; k < K_; ++k) {
        const float* lw = lo + k * CMID;
        float4_ w0 = *(const float4_*)(lw + 0);
        float4_ w1 = *(const float4_*)(lw + 4);
        float4_ w2 = *(const float4_*)(lw + 8);
        float4_ w3 = *(const float4_*)(lw + 12);
        #pragma unroll
        for (int e = 0; e < 4; ++e) {
            acc[0  + e] += f[k] * w0[e];
            acc[4  + e] += f[k] * w1[e];
            acc[8  + e] += f[k] * w2[e];
            acc[12 + e] += f[k] * w3[e];
        }
    }

    // ---- tail channels FIRST (last reader of wn region 0..255) ----
    const int t  = lane >> 4;
    const int wt = lane & 15;
    if (lane < 48) {
        float acc2 = 0.f;
        #pragma unroll
        for (int k = 0; k < K_; ++k) {
            float a0 = padd[k * 3 + 0];                  // uniform s_loads
            float a1 = padd[k * 3 + 1];
            float a2 = padd[k * 3 + 2];
            float av = (t == 0) ? a0 : (t == 1) ? a1 : a2;
            acc2 += av * lo[k * CMID + wt];              // broadcast x3, conflict-free
        }
        lo[(CIN + t) * LSTR + wt] = acc2;                // rows 64..66: no overlap
    }

    // ---- main transpose (overwrites wn region — now dead) ----
    #pragma unroll
    for (int w = 0; w < CMID; ++w)
        lo[lane * LSTR + w] = acc[w];                    // 17-stride: <=2-way banks

    // ---- readback in store-contiguous order; NT stores 4x1KB + 192B ----
    float* pout = out + (long)bp * (COUT * CMID);
    const int q = lane >> 2;
    const int r = lane & 3;
    #pragma unroll
    for (int p = 0; p < 4; ++p) {
        const float* src = lo + (p * 16 + q) * LSTR + 4 * r;
        float4_ v = { src[0], src[1], src[2], src[3] };
        __builtin_nontemporal_store(v, (float4_*)(pout + p * 256 + lane * 4));
    }
    if (lane < 12) {
        const float* src = lo + (CIN + q) * LSTR + 4 * r;
        float4_ v = { src[0], src[1], src[2], src[3] };
        __builtin_nontemporal_store(v, (float4_*)(pout + 1024 + lane * 4));
    }
}

extern "C" void kernel_launch(void* const* d_in, const int* in_sizes, int n_in,
                              void* d_out, int out_size, void* d_ws, size_t ws_size,
                              hipStream_t stream) {
    const float* in_feats = (const float*)d_in[0];
    const int*   ninds    = (const int*)d_in[1];
    const float* wnp      = (const float*)d_in[2];
    const float* addl     = (const float*)d_in[3];
    float*       outp     = (float*)d_out;

    const int total_points = B_ * M_;            // 80000
    dim3 grid(total_points / PPB);               // 20000 blocks, 1 point/wave
    dim3 block(256);
    pconv_kernel<<<grid, block, 0, stream>>>(in_feats, ninds, wnp, addl, outp);
}

// Round 16
// 104.178 us; speedup vs baseline: 20.7316x; 20.0962x over previous
//
#include <hip/hip_runtime.h>

#define B_    4
#define N_    20000
#define M_    20000
#define K_    16
#define CIN   64
#define CMID  16
#define COUT  67            // CIN + 3 additional channels
#define PPB   4             // one point per wave, 4 waves per block
#define LSTR  17            // padded LDS transpose stride (f32)
#define NXCD  8

typedef float float4_ __attribute__((ext_vector_type(4)));

// EXACT revert to the R13 winner (103.8 us). bounds(256,6) -> VGPR cap 85:
// fits the ~85 live regs (f[16]+acc[16]+addressing). Bounds 7/8 spill
// catastrophically (R14/R15: VGPR 32-36, 8 GB scratch traffic, ~2100 us).

__global__ __launch_bounds__(256, 6) void pconv_kernel(
    const float* __restrict__ in_feats,   // [B, N, 64]
    const int*   __restrict__ inds,       // [B, M, 16]
    const float* __restrict__ wn,         // [B, M, 16, 16]
    const float* __restrict__ addl,       // [B, M, 16, 3]
    float*       __restrict__ out)        // [B, M, 1072]
{
    __shared__ float lds_out[PPB][(COUT + 1) * LSTR];   // 4 x 4624 B transpose buf
    __shared__ float lds_wn [PPB][K_ * CMID];           // 4 x 1 KB

    const int tid  = threadIdx.x;
    const int lane = tid & 63;
    const int wav  = tid >> 6;

    // bijective XCD swizzle: 20000 blocks -> 2500 contiguous per XCD slot
    const int qx  = gridDim.x / NXCD;                    // 2500
    const int swz = (blockIdx.x % NXCD) * qx + blockIdx.x / NXCD;

    const int bp = __builtin_amdgcn_readfirstlane(swz * PPB + wav);
    const int b  = bp / M_;

    const int*   pinds = inds + (long)bp * K_;
    const float* pwn   = wn   + (long)bp * (K_ * CMID);
    const float* padd  = addl + (long)bp * (K_ * 3);
    const float* bfeat = in_feats + (long)b * N_ * CIN;

    // ---- wn: read-once stream -> non-temporal load (don't pollute L2) ----
    float4_ wstage = __builtin_nontemporal_load((const float4_*)pwn + lane);

    // ---- 16 neighbor indices -> SGPRs ----
    int idxs[K_];
    #pragma unroll
    for (int k = 0; k < K_; ++k) idxs[k] = pinds[k];

    // ---- issue ALL 16 gathers before any consumption (max MLP) ----
    float f[K_];
    #pragma unroll
    for (int k = 0; k < K_; ++k)
        f[k] = bfeat[(long)idxs[k] * CIN + lane];        // 256B coalesced each

    // stage wn to LDS (waits only on wstage's own vmcnt slot)
    *(float4_*)(&lds_wn[wav][lane * 4]) = wstage;

    // ---- FMA phase: wn via uniform ds_read_b128 broadcasts ----
    float acc[CMID];
    #pragma unroll
    for (int w = 0; w < CMID; ++w) acc[w] = 0.f;

    #pragma unroll
    for (int k = 0; k < K_; ++k) {
        const float* lw = &lds_wn[wav][k * CMID];
        float4_ w0 = *(const float4_*)(lw + 0);
        float4_ w1 = *(const float4_*)(lw + 4);
        float4_ w2 = *(const float4_*)(lw + 8);
        float4_ w3 = *(const float4_*)(lw + 12);
        #pragma unroll
        for (int e = 0; e < 4; ++e) {
            acc[0  + e] += f[k] * w0[e];
            acc[4  + e] += f[k] * w1[e];
            acc[8  + e] += f[k] * w2[e];
            acc[12 + e] += f[k] * w3[e];
        }
    }

    // ---- transpose via padded LDS (17-f32 stride: <=2-way banks, free) ----
    float* lo = &lds_out[wav][0];
    #pragma unroll
    for (int w = 0; w < CMID; ++w)
        lo[lane * LSTR + w] = acc[w];

    // tail channels c = 64+t (t=lane>>4, wt=lane&15), lanes 0..47
    const int t  = lane >> 4;
    const int wt = lane & 15;
    if (lane < 48) {
        float acc2 = 0.f;
        #pragma unroll
        for (int k = 0; k < K_; ++k) {
            float a0 = padd[k * 3 + 0];                  // uniform s_loads
            float a1 = padd[k * 3 + 1];
            float a2 = padd[k * 3 + 2];
            float av = (t == 0) ? a0 : (t == 1) ? a1 : a2;
            acc2 += av * lds_wn[wav][k * CMID + wt];     // broadcast x3, conflict-free
        }
        lo[(CIN + t) * LSTR + wt] = acc2;
    }

    // ---- readback in store-contiguous order; NT stores 4x1KB + 192B ----
    // write-once stream -> non-temporal: keep the 343MB output stream from
    // evicting the gather table out of each XCD's 4MB L2
    float* pout = out + (long)bp * (COUT * CMID);
    const int q = lane >> 2;
    const int r = lane & 3;
    #pragma unroll
    for (int p = 0; p < 4; ++p) {
        const float* src = lo + (p * 16 + q) * LSTR + 4 * r;
        float4_ v = { src[0], src[1], src[2], src[3] };
        __builtin_nontemporal_store(v, (float4_*)(pout + p * 256 + lane * 4));
    }
    if (lane < 12) {
        const float* src = lo + (CIN + q) * LSTR + 4 * r;
        float4_ v = { src[0], src[1], src[2], src[3] };
        __builtin_nontemporal_store(v, (float4_*)(pout + 1024 + lane * 4));
    }
}

extern "C" void kernel_launch(void* const* d_in, const int* in_sizes, int n_in,
                              void* d_out, int out_size, void* d_ws, size_t ws_size,
                              hipStream_t stream) {
    const float* in_feats = (const float*)d_in[0];
    const int*   ninds    = (const int*)d_in[1];
    const float* wnp      = (const float*)d_in[2];
    const float* addl     = (const float*)d_in[3];
    float*       outp     = (float*)d_out;

    const int total_points = B_ * M_;            // 80000
    dim3 grid(total_points / PPB);               // 20000 blocks, 1 point/wave
    dim3 block(256);
    pconv_kernel<<<grid, block, 0, stream>>>(in_feats, ninds, wnp, addl, outp);
}